// Round 2
// baseline (83.526 us; speedup 1.0000x reference)
//
#include <hip/hip_runtime.h>

// Tree evaluation: N=2048 nodes, node j in [1024,2047] = leaf, [1,1023] = internal.
// Internal j: val = rotate(homog(V[2j], V[2j+1], frac[2048-2j], frac[2047-2j]), theta[j])
// Leaf j:     val = rotate(j%2==0 ? phase1[b] : phase2[b], theta[j])
// Output per batch b: node 1's 6-vector. prop_w/prop_f in the reference are dead code.
//
// Structure: 2 waves per batch element. Each lane evaluates the 15-node subtree
// of one level-7 node in registers (no LDS, full lane efficiency), then 6
// intra-wave shuffle steps reduce 64 level-7 nodes -> node 2 (wave even) or
// node 3 (wave odd). One barrier + tiny LDS exchange for the root.

#define N_NODES 2048

// D = R^T M R, R = [[a,bb,d],[bb,a,-d],[-d,d,e]], M symmetric (m0 m1 m2; m1 m3 m4; m2 m4 m5)
__device__ __forceinline__ void rotate6(const float* m, float4 r, float* o) {
    float a = r.x, bb = r.y, d = r.z, e = r.w;
    float T00 = m[0]*a  + m[1]*bb - m[2]*d;
    float T01 = m[0]*bb + m[1]*a  + m[2]*d;
    float T02 = (m[0]-m[1])*d + m[2]*e;
    float T10 = m[1]*a  + m[3]*bb - m[4]*d;
    float T11 = m[1]*bb + m[3]*a  + m[4]*d;
    float T12 = (m[1]-m[3])*d + m[4]*e;
    float T20 = m[2]*a  + m[4]*bb - m[5]*d;
    float T21 = m[2]*bb + m[4]*a  + m[5]*d;
    float T22 = (m[2]-m[4])*d + m[5]*e;
    o[0] = a*T00 + bb*T10 - d*T20;
    o[1] = a*T01 + bb*T11 - d*T21;
    o[2] = a*T02 + bb*T12 - d*T22;
    o[3] = bb*T01 + a*T11 + d*T21;
    o[4] = bb*T02 + a*T12 + d*T22;
    o[5] = (T02 - T12)*d + e*T22;
}

__device__ __forceinline__ void homog6(const float* D1, const float* D2,
                                       float f1, float f2, float* o) {
    float gamma = f1*D2[0] + f2*D1[0];
    float g = (gamma == 0.0f) ? 1.0f : gamma;
    float rg = 1.0f / g;
    float ff = f1*f2*rg;
    o[0] = D1[0]*D2[0]*rg;
    o[1] = (f1*D1[1]*D2[0] + f2*D2[1]*D1[0])*rg;
    o[2] = (f1*D1[2]*D2[0] + f2*D2[2]*D1[0])*rg;
    float t1 = D1[1]-D2[1];
    float t2 = D1[2]-D2[2];
    o[3] = f1*D1[3] + f2*D2[3] - ff*t1*t1;
    o[4] = f1*D1[4] + f2*D2[4] - ff*t2*t1;
    o[5] = f1*D1[5] + f2*D2[5] - ff*t2*t2;
}

// level-9 node j9 from its two leaf children (leaf 2*j9 even -> phase1, 2*j9+1 odd -> phase2)
__device__ __forceinline__ void subtree9(const float* p1, const float* p2,
                                         const float4* __restrict__ rot,
                                         const float2* __restrict__ fr,
                                         int j9, float* outD) {
    float L[6], R[6], H[6];
    rotate6(p1, rot[2*j9],   L);
    rotate6(p2, rot[2*j9+1], R);
    float2 f = fr[j9];
    homog6(L, R, f.x, f.y, H);
    rotate6(H, rot[j9], outD);
}

// level-8 node j8 from its 7-node subtree
__device__ __forceinline__ void node8(const float* p1, const float* p2,
                                      const float4* __restrict__ rot,
                                      const float2* __restrict__ fr,
                                      int j8, float* outD) {
    float A[6], B[6], H[6];
    subtree9(p1, p2, rot, fr, 2*j8,   A);
    subtree9(p1, p2, rot, fr, 2*j8+1, B);
    float2 f = fr[j8];
    homog6(A, B, f.x, f.y, H);
    rotate6(H, rot[j8], outD);
}

__global__ void setup_kernel(const float* __restrict__ theta,
                             const float* __restrict__ fractions,
                             float4* __restrict__ rot, float2* __restrict__ fr) {
    int j = blockIdx.x * blockDim.x + threadIdx.x;
    if (j >= 1 && j < N_NODES) {
        float t = theta[j];
        float c = cosf(t), s = sinf(t);
        float a = c*c, bb = s*s;
        float d = sqrtf(2.0f) * c * s;
        rot[j] = make_float4(a, bb, d, a - bb);
    }
    if (j >= 1 && j < N_NODES/2) {
        fr[j] = make_float2(fractions[N_NODES - 2*j], fractions[N_NODES - 2*j - 1]);
    }
}

__global__ __launch_bounds__(256, 4) void tree_kernel(
    const float* __restrict__ phase1, const float* __restrict__ phase2,
    const float4* __restrict__ rot, const float2* __restrict__ fr,
    float* __restrict__ out)
{
    const int tid  = threadIdx.x;
    const int wid  = tid >> 6;      // 0..3
    const int lane = tid & 63;
    const int half = wid & 1;       // which half of this batch's level-7 nodes
    const int bloc = wid >> 1;      // batch slot within block (0 or 1)
    const int b    = blockIdx.x * 2 + bloc;

    float p1[6], p2[6];
#pragma unroll
    for (int k = 0; k < 6; ++k) { p1[k] = phase1[b*6+k]; p2[k] = phase2[b*6+k]; }

    // Register phase: this lane's level-7 node (15 node-ops, zero LDS/barriers).
    float A[6], Bv[6], H[6], v[6];
    {
        int j7 = 128 + half*64 + lane;
        node8(p1, p2, rot, fr, 2*j7,   A);
        node8(p1, p2, rot, fr, 2*j7+1, Bv);
        float2 f = fr[j7];
        homog6(A, Bv, f.x, f.y, H);
        rotate6(H, rot[j7], v);
    }

    // Intra-wave shuffle reduction: 6 levels, no barriers.
    // Wave (half=0) holds nodes [128,192) -> node 2; (half=1) [192,256) -> node 3.
    int jbase = 128 + half*64;
    int width = 64;
#pragma unroll
    for (int s = 0; s < 6; ++s) {
        float ce[6], co[6];
#pragma unroll
        for (int k = 0; k < 6; ++k) {
            ce[k] = __shfl(v[k], 2*lane,     64);
            co[k] = __shfl(v[k], 2*lane + 1, 64);
        }
        jbase >>= 1;
        width >>= 1;
        if (lane < width) {
            int j = jbase + lane;
            float2 f = fr[j];
            homog6(ce, co, f.x, f.y, H);
            rotate6(H, rot[j], v);
        }
    }

    // Combine node 2 / node 3 across the wave pair; root op by 2 threads.
    __shared__ float comb[2][2][6];   // [batch slot][node-2/3][component]
    if (lane == 0) {
#pragma unroll
        for (int k = 0; k < 6; ++k) comb[bloc][half][k] = v[k];
    }
    __syncthreads();

    if (tid < 2) {
        float D1[6], D2[6], Hh[6], Dn[6];
#pragma unroll
        for (int k = 0; k < 6; ++k) { D1[k] = comb[tid][0][k]; D2[k] = comb[tid][1][k]; }
        float2 f = fr[1];
        homog6(D1, D2, f.x, f.y, Hh);
        rotate6(Hh, rot[1], Dn);
        int bb = blockIdx.x * 2 + tid;
#pragma unroll
        for (int k = 0; k < 6; ++k) out[bb*6 + k] = Dn[k];
    }
}

extern "C" void kernel_launch(void* const* d_in, const int* in_sizes, int n_in,
                              void* d_out, int out_size, void* d_ws, size_t ws_size,
                              hipStream_t stream) {
    const float* phase1    = (const float*)d_in[0];
    const float* phase2    = (const float*)d_in[1];
    const float* theta     = (const float*)d_in[2];
    // d_in[3] activation, d_in[4] weight, d_in[6] left, d_in[7] right: dead code / fixed tree
    const float* fractions = (const float*)d_in[5];
    float* out = (float*)d_out;

    const int B = in_sizes[0] / 6;

    float4* rot = (float4*)d_ws;                                     // 2048 * 16B = 32 KB
    float2* fr  = (float2*)((char*)d_ws + N_NODES * sizeof(float4)); // 1024 * 8B  =  8 KB

    hipLaunchKernelGGL(setup_kernel, dim3((N_NODES + 255) / 256), dim3(256), 0, stream,
                       theta, fractions, rot, fr);
    hipLaunchKernelGGL(tree_kernel, dim3(B / 2), dim3(256), 0, stream,
                       phase1, phase2, rot, fr, out);
}